// Round 2
// baseline (1047.761 us; speedup 1.0000x reference)
//
#include <hip/hip_runtime.h>
#include <hip/hip_bf16.h>

#define D_DIM 256
#define EPS_LN 1e-5f
#define NEG_SLOPE 0.2f

typedef __bf16 bf16x8 __attribute__((ext_vector_type(8)));
typedef unsigned short ushortx8 __attribute__((ext_vector_type(8)));
typedef unsigned short ushortx4 __attribute__((ext_vector_type(4)));
typedef float floatx4 __attribute__((ext_vector_type(4)));

__device__ inline unsigned short f2bf(float f) {
    __hip_bfloat16 h = __float2bfloat16(f);
    return __builtin_bit_cast(unsigned short, h);
}
__device__ inline float bf2f(unsigned short u) {
    unsigned int x = ((unsigned int)u) << 16;
    return __builtin_bit_cast(float, x);
}

// ---------------------------------------------------------------------------
// Transpose + bf16-convert three 256x256 weight matrices (coalesced both ways
// via 64x65 LDS tile).  grid = (16, 3), block = 256.
// ---------------------------------------------------------------------------
__global__ __launch_bounds__(256) void wtrans_kernel(
        const float* __restrict__ W0, const float* __restrict__ W1,
        const float* __restrict__ W2, unsigned short* __restrict__ T0,
        unsigned short* __restrict__ T1, unsigned short* __restrict__ T2) {
    const float* W = (blockIdx.y == 0) ? W0 : (blockIdx.y == 1) ? W1 : W2;
    unsigned short* T = (blockIdx.y == 0) ? T0 : (blockIdx.y == 1) ? T1 : T2;
    __shared__ float lds[64][65];
    const int tx = blockIdx.x & 3;    // tile col
    const int ty = blockIdx.x >> 2;   // tile row
    const int t = threadIdx.x;
    const int r = t >> 6;             // 0..3
    const int c = t & 63;
#pragma unroll
    for (int i = 0; i < 16; ++i) {
        int row = ty * 64 + r + i * 4;
        lds[r + i * 4][c] = W[row * 256 + tx * 64 + c];
    }
    __syncthreads();
#pragma unroll
    for (int i = 0; i < 16; ++i) {
        int orow = tx * 64 + r + i * 4;   // output row = original col
        T[orow * 256 + ty * 64 + c] = f2bf(lds[c][r + i * 4]);
    }
}

// ---------------------------------------------------------------------------
// LayerNorm + ReLU, one wave per row of 256, float4 per lane
// ---------------------------------------------------------------------------
__global__ __launch_bounds__(256) void ln_relu_kernel(
        const float* __restrict__ x, const float* __restrict__ g,
        const float* __restrict__ b, float* __restrict__ y, int nrows) {
    int row = blockIdx.x * 4 + (threadIdx.x >> 6);
    if (row >= nrows) return;
    int lane = threadIdx.x & 63;
    float4 v = ((const float4*)(x + (size_t)row * D_DIM))[lane];
    float s = v.x + v.y + v.z + v.w;
    float s2 = v.x * v.x + v.y * v.y + v.z * v.z + v.w * v.w;
#pragma unroll
    for (int m = 32; m >= 1; m >>= 1) {
        s += __shfl_xor(s, m, 64);
        s2 += __shfl_xor(s2, m, 64);
    }
    float mean = s * (1.f / D_DIM);
    float var = s2 * (1.f / D_DIM) - mean * mean;
    float rstd = rsqrtf(var + EPS_LN);
    float4 gv = ((const float4*)g)[lane];
    float4 bv = ((const float4*)b)[lane];
    float4 o;
    o.x = fmaxf((v.x - mean) * rstd * gv.x + bv.x, 0.f);
    o.y = fmaxf((v.y - mean) * rstd * gv.y + bv.y, 0.f);
    o.z = fmaxf((v.z - mean) * rstd * gv.z + bv.z, 0.f);
    o.w = fmaxf((v.w - mean) * rstd * gv.w + bv.w, 0.f);
    ((float4*)(y + (size_t)row * D_DIM))[lane] = o;
}

// ---------------------------------------------------------------------------
// bf16-MFMA GEMM: out[M,256] = A[M,256] @ W[256,256] + bias (+ residual)
// A fp32, W pre-transposed bf16 (Wt[n][k]).  Block tile 128x128, 4 waves,
// wave tile 64x64 (4x4 of 16x16x32 MFMA).  Double-buffered LDS (stride 40),
// register prefetch of next k-tile: ONE barrier per K-iteration and global
// latency overlapped with MFMA.
// ---------------------------------------------------------------------------
template <int OUT_BF16, int HAS_RES>
__global__ __launch_bounds__(256) void gemm256_kernel(
        const float* __restrict__ A, const unsigned short* __restrict__ Wt,
        const float* __restrict__ bias, const float* __restrict__ res,
        void* __restrict__ out, int M) {
    __shared__ unsigned short As[2][128 * 40];
    __shared__ unsigned short Bs[2][128 * 40];
    const int n0 = blockIdx.x * 128;
    const int m0 = blockIdx.y * 128;
    const int t = threadIdx.x;
    const int lane = t & 63;
    const int wave = t >> 6;
    const int q = lane >> 4;
    const int l16 = lane & 15;
    const int wm = (wave & 1) * 64;
    const int wn = (wave >> 1) * 64;
    const int sm = t >> 1;        // staging row 0..127
    const int sh = t & 1;         // staging half (16 elems)

    const bool arow_ok = (m0 + sm) < M;
    const float* aptr = A + (size_t)(m0 + sm) * 256 + sh * 16;
    const unsigned short* bptr = Wt + (size_t)(n0 + sm) * 256 + sh * 16;

    float4 a_reg[4];
    ushortx8 b_reg[2];

    auto g_load = [&](int kt) {
        if (arow_ok) {
            const float4* ap = (const float4*)(aptr + kt * 32);
            a_reg[0] = ap[0]; a_reg[1] = ap[1]; a_reg[2] = ap[2]; a_reg[3] = ap[3];
        }
        const ushortx8* bp = (const ushortx8*)(bptr + kt * 32);
        b_reg[0] = bp[0]; b_reg[1] = bp[1];
    };
    auto s_store = [&](int buf) {
        unsigned short tmp[16];
        if (arow_ok) {
#pragma unroll
            for (int i = 0; i < 4; ++i) {
                tmp[i * 4 + 0] = f2bf(a_reg[i].x);
                tmp[i * 4 + 1] = f2bf(a_reg[i].y);
                tmp[i * 4 + 2] = f2bf(a_reg[i].z);
                tmp[i * 4 + 3] = f2bf(a_reg[i].w);
            }
        } else {
#pragma unroll
            for (int i = 0; i < 16; ++i) tmp[i] = 0;
        }
        *(ushortx8*)&As[buf][sm * 40 + sh * 16] = *(ushortx8*)&tmp[0];
        *(ushortx8*)&As[buf][sm * 40 + sh * 16 + 8] = *(ushortx8*)&tmp[8];
        *(ushortx8*)&Bs[buf][sm * 40 + sh * 16] = b_reg[0];
        *(ushortx8*)&Bs[buf][sm * 40 + sh * 16 + 8] = b_reg[1];
    };

    floatx4 acc[4][4] = {};

    g_load(0);
    s_store(0);
    __syncthreads();

    for (int kt = 0; kt < 8; ++kt) {
        const int cur = kt & 1;
        if (kt < 7) g_load(kt + 1);            // in flight during MFMA
        bf16x8 af[4], bfr[4];
#pragma unroll
        for (int mi = 0; mi < 4; ++mi)
            af[mi] = __builtin_bit_cast(bf16x8,
                *(const ushortx8*)&As[cur][(wm + mi * 16 + l16) * 40 + q * 8]);
#pragma unroll
        for (int ni = 0; ni < 4; ++ni)
            bfr[ni] = __builtin_bit_cast(bf16x8,
                *(const ushortx8*)&Bs[cur][(wn + ni * 16 + l16) * 40 + q * 8]);
#pragma unroll
        for (int mi = 0; mi < 4; ++mi)
#pragma unroll
            for (int ni = 0; ni < 4; ++ni)
                acc[mi][ni] = __builtin_amdgcn_mfma_f32_16x16x32_bf16(
                    af[mi], bfr[ni], acc[mi][ni], 0, 0, 0);
        if (kt < 7) {
            s_store(cur ^ 1);
            __syncthreads();
        }
    }

    // epilogue: D[row = q*4+r][col = l16] per 16x16 tile
#pragma unroll
    for (int mi = 0; mi < 4; ++mi) {
#pragma unroll
        for (int ni = 0; ni < 4; ++ni) {
            int col = n0 + wn + ni * 16 + l16;
            float bcol = bias[col];
#pragma unroll
            for (int r = 0; r < 4; ++r) {
                int row = m0 + wm + mi * 16 + q * 4 + r;
                if (row < M) {
                    float v = acc[mi][ni][r] + bcol;
                    if (HAS_RES) v += res[(size_t)row * 256 + col];
                    if (OUT_BF16)
                        ((unsigned short*)out)[(size_t)row * 256 + col] = f2bf(v);
                    else
                        ((float*)out)[(size_t)row * 256 + col] = v;
                }
            }
        }
    }
}

// ---------------------------------------------------------------------------
// CSR build: histogram, single-block scan, scatter
// ---------------------------------------------------------------------------
__global__ void hist_kernel(const int* __restrict__ tgt, int* __restrict__ counts, int E) {
    int i = blockIdx.x * 256 + threadIdx.x;
    if (i < E) atomicAdd(&counts[tgt[i]], 1);
}

__global__ __launch_bounds__(1024) void scan_kernel(
        const int* __restrict__ counts, int* __restrict__ offs, int n) {
    __shared__ int lds[1024];
    int t = threadIdx.x;
    int CH = (n + 1023) >> 10;
    int beg = t * CH, end = min(beg + CH, n);
    int s = 0;
    for (int i = beg; i < end; ++i) s += counts[i];
    lds[t] = s;
    __syncthreads();
    for (int off = 1; off < 1024; off <<= 1) {
        int v = (t >= off) ? lds[t - off] : 0;
        __syncthreads();
        lds[t] += v;
        __syncthreads();
    }
    int run = lds[t] - s;   // exclusive prefix
    for (int i = beg; i < end; ++i) { offs[i] = run; run += counts[i]; }
    if (t == 1023) offs[n] = lds[1023];
}

__global__ void scatter_kernel(const int* __restrict__ tgt, const int* __restrict__ offs,
                               int* __restrict__ cursor, int* __restrict__ elist, int E) {
    int i = blockIdx.x * 256 + threadIdx.x;
    if (i < E) {
        int tg = tgt[i];
        int p = atomicAdd(&cursor[tg], 1);
        elist[offs[tg] + p] = i;
    }
}

// ---------------------------------------------------------------------------
// Per-target fused: edge softmax + aggregation + gat_bias + residual + LN2 + relu
// One wave per target.  Lane l owns the 4 consecutive features d = 4l..4l+3
// (head = l>>3): per-head dot reduces with shfl_xor {1,2,4}; all global
// accesses are 8-16B vectorized; next edge's row is prefetched.
// ---------------------------------------------------------------------------
__global__ __launch_bounds__(256) void aggregate_kernel(
        const unsigned short* __restrict__ xl, const float* __restrict__ xr,
        const float* __restrict__ prev, const int* __restrict__ esrc,
        const int* __restrict__ elist, const int* __restrict__ offs,
        const float* __restrict__ att, const float* __restrict__ gbias,
        const float* __restrict__ g2, const float* __restrict__ b2,
        float* __restrict__ x_skip, float* __restrict__ h2, int nsp) {
    int tgt = blockIdx.x * 4 + (threadIdx.x >> 6);
    if (tgt >= nsp) return;
    int lane = threadIdx.x & 63;
    float4 xrv = ((const float4*)(xr + (size_t)tgt * D_DIM))[lane];
    float4 attv = ((const float4*)att)[lane];
    float acc0 = 0.f, acc1 = 0.f, acc2 = 0.f, acc3 = 0.f, den = 0.f;
    int beg = offs[tgt], end = offs[tgt + 1];

    ushortx4 row = {};
    if (beg < end) {
        int e = elist[beg];
        int src = esrc[e];
        row = ((const ushortx4*)(xl + (size_t)src * D_DIM))[lane];
    }
    for (int i = beg; i < end; ++i) {
        ushortx4 row_n = {};
        if (i + 1 < end) {
            int e1 = elist[i + 1];
            int s1 = esrc[e1];
            row_n = ((const ushortx4*)(xl + (size_t)s1 * D_DIM))[lane];
        }
        float x0 = bf2f(row[0]), x1 = bf2f(row[1]), x2 = bf2f(row[2]), x3 = bf2f(row[3]);
        float t0 = x0 + xrv.x, t1 = x1 + xrv.y, t2 = x2 + xrv.z, t3 = x3 + xrv.w;
        t0 = t0 > 0.f ? t0 : NEG_SLOPE * t0;
        t1 = t1 > 0.f ? t1 : NEG_SLOPE * t1;
        t2 = t2 > 0.f ? t2 : NEG_SLOPE * t2;
        t3 = t3 > 0.f ? t3 : NEG_SLOPE * t3;
        float p = t0 * attv.x + t1 * attv.y + t2 * attv.z + t3 * attv.w;
        p += __shfl_xor(p, 1, 64);
        p += __shfl_xor(p, 2, 64);
        p += __shfl_xor(p, 4, 64);      // full per-head dot, replicated in 8-lane group
        float ex = __expf(p);
        den += ex;
        acc0 += ex * x0; acc1 += ex * x1; acc2 += ex * x2; acc3 += ex * x3;
        row = row_n;
    }
    float rden = 1.f / (den + 1e-16f);
    float4 pv = ((const float4*)(prev + (size_t)tgt * D_DIM))[lane];
    float4 gb = ((const float4*)gbias)[lane];
    float v0 = pv.x + acc0 * rden + gb.x;
    float v1 = pv.y + acc1 * rden + gb.y;
    float v2 = pv.z + acc2 * rden + gb.z;
    float v3 = pv.w + acc3 * rden + gb.w;
    float s = v0 + v1 + v2 + v3;
    float s2 = v0 * v0 + v1 * v1 + v2 * v2 + v3 * v3;
#pragma unroll
    for (int m = 32; m >= 1; m >>= 1) {
        s += __shfl_xor(s, m, 64);
        s2 += __shfl_xor(s2, m, 64);
    }
    float mean = s * (1.f / D_DIM);
    float var = s2 * (1.f / D_DIM) - mean * mean;
    float rstd = rsqrtf(var + EPS_LN);
    float4 g2v = ((const float4*)g2)[lane];
    float4 b2v = ((const float4*)b2)[lane];
    float4 xs; xs.x = v0; xs.y = v1; xs.z = v2; xs.w = v3;
    ((float4*)(x_skip + (size_t)tgt * D_DIM))[lane] = xs;
    float4 h;
    h.x = fmaxf((v0 - mean) * rstd * g2v.x + b2v.x, 0.f);
    h.y = fmaxf((v1 - mean) * rstd * g2v.y + b2v.y, 0.f);
    h.z = fmaxf((v2 - mean) * rstd * g2v.z + b2v.z, 0.f);
    h.w = fmaxf((v3 - mean) * rstd * g2v.w + b2v.w, 0.f);
    ((float4*)(h2 + (size_t)tgt * D_DIM))[lane] = h;
}

// ---------------------------------------------------------------------------
extern "C" void kernel_launch(void* const* d_in, const int* in_sizes, int n_in,
                              void* d_out, int out_size, void* d_ws, size_t ws_size,
                              hipStream_t stream) {
    const float* proj = (const float*)d_in[0];
    const float* prev = (const float*)d_in[1];
    const float* Wl   = (const float*)d_in[2];
    const float* bl   = (const float*)d_in[3];
    const float* Wr   = (const float*)d_in[4];
    const float* br   = (const float*)d_in[5];
    const float* att  = (const float*)d_in[6];
    const float* gbias= (const float*)d_in[7];
    const float* ln1g = (const float*)d_in[8];
    const float* ln1b = (const float*)d_in[9];
    const float* ln2g = (const float*)d_in[10];
    const float* ln2b = (const float*)d_in[11];
    const float* Wm   = (const float*)d_in[12];
    const float* mb   = (const float*)d_in[13];
    const int* esrc   = (const int*)d_in[14];
    const int* etgt   = (const int*)d_in[15];

    const int NP = in_sizes[0] / D_DIM;   // 400000
    const int NS = in_sizes[1] / D_DIM;   // 40000
    const int E  = in_sizes[14];          // 400000

    char* base = (char*)d_ws;
    size_t off = 0;
    auto carve = [&](size_t bytes) {
        char* p = base + off;
        off += (bytes + 255) & ~(size_t)255;
        return p;
    };
    unsigned short* xl    = (unsigned short*)carve((size_t)NP * D_DIM * 2);
    float* x_agg          = (float*)carve((size_t)NS * D_DIM * 4);
    float* xr             = (float*)carve((size_t)NS * D_DIM * 4);
    float* x_skip         = (float*)carve((size_t)NS * D_DIM * 4);
    float* h2             = (float*)carve((size_t)NS * D_DIM * 4);
    unsigned short* Wt_l  = (unsigned short*)carve((size_t)D_DIM * D_DIM * 2);
    unsigned short* Wt_r  = (unsigned short*)carve((size_t)D_DIM * D_DIM * 2);
    unsigned short* Wt_m  = (unsigned short*)carve((size_t)D_DIM * D_DIM * 2);
    int* counts           = (int*)carve((size_t)NS * 4 * 2);
    int* cursor           = counts + NS;
    int* offs             = (int*)carve((size_t)(NS + 1) * 4);
    int* elist            = (int*)carve((size_t)E * 4);

    hipMemsetAsync(counts, 0, (size_t)NS * 4 * 2, stream);

    wtrans_kernel<<<dim3(16, 3), 256, 0, stream>>>(Wl, Wr, Wm, Wt_l, Wt_r, Wt_m);

    ln_relu_kernel<<<(NS + 3) / 4, 256, 0, stream>>>(prev, ln1g, ln1b, x_agg, NS);

    // xr = x_agg @ Wr + br (fp32 out)
    gemm256_kernel<0, 0><<<dim3(2, (NS + 127) / 128), 256, 0, stream>>>(
        x_agg, Wt_r, br, nullptr, (void*)xr, NS);

    // xl = proj @ Wl + bl (bf16 out)
    gemm256_kernel<1, 0><<<dim3(2, (NP + 127) / 128), 256, 0, stream>>>(
        proj, Wt_l, bl, nullptr, (void*)xl, NP);

    // CSR build
    hist_kernel<<<(E + 255) / 256, 256, 0, stream>>>(etgt, counts, E);
    scan_kernel<<<1, 1024, 0, stream>>>(counts, offs, NS);
    scatter_kernel<<<(E + 255) / 256, 256, 0, stream>>>(etgt, offs, cursor, elist, E);

    // fused edge softmax + aggregation + residual + LN2 + relu
    aggregate_kernel<<<(NS + 3) / 4, 256, 0, stream>>>(
        xl, xr, prev, esrc, elist, offs, att, gbias, ln2g, ln2b, x_skip, h2, NS);

    // out = x_skip + h2 @ mlp_W + mlp_b
    gemm256_kernel<0, 1><<<dim3(2, (NS + 127) / 128), 256, 0, stream>>>(
        h2, Wt_m, mb, x_skip, d_out, NS);
}

// Round 3
// 970.023 us; speedup vs baseline: 1.0801x; 1.0801x over previous
//
#include <hip/hip_runtime.h>
#include <hip/hip_bf16.h>

#define D_DIM 256
#define EPS_LN 1e-5f
#define NEG_SLOPE 0.2f

typedef __bf16 bf16x8 __attribute__((ext_vector_type(8)));
typedef unsigned short ushortx8 __attribute__((ext_vector_type(8)));
typedef unsigned short ushortx4 __attribute__((ext_vector_type(4)));
typedef float floatx4 __attribute__((ext_vector_type(4)));

__device__ inline unsigned short f2bf(float f) {
    __hip_bfloat16 h = __float2bfloat16(f);
    return __builtin_bit_cast(unsigned short, h);
}
__device__ inline float bf2f(unsigned short u) {
    unsigned int x = ((unsigned int)u) << 16;
    return __builtin_bit_cast(float, x);
}

// 16B-per-lane async global->LDS copy.  LDS dest is wave-uniform base +
// lane*16 (HW semantics); global src is per-lane (carries our swizzle).
__device__ __forceinline__ void async_copy16(const void* g, void* l) {
    __builtin_amdgcn_global_load_lds(
        (const __attribute__((address_space(1))) unsigned int*)g,
        (__attribute__((address_space(3))) unsigned int*)l, 16, 0, 0);
}

__device__ inline bf16x8 cvt_frag(float4 a, float4 b) {
    ushortx8 u;
    u[0] = f2bf(a.x); u[1] = f2bf(a.y); u[2] = f2bf(a.z); u[3] = f2bf(a.w);
    u[4] = f2bf(b.x); u[5] = f2bf(b.y); u[6] = f2bf(b.z); u[7] = f2bf(b.w);
    return __builtin_bit_cast(bf16x8, u);
}

// ---------------------------------------------------------------------------
// Transpose + bf16-convert three 256x256 weight matrices (64x65 LDS tile).
// ---------------------------------------------------------------------------
__global__ __launch_bounds__(256) void wtrans_kernel(
        const float* __restrict__ W0, const float* __restrict__ W1,
        const float* __restrict__ W2, unsigned short* __restrict__ T0,
        unsigned short* __restrict__ T1, unsigned short* __restrict__ T2) {
    const float* W = (blockIdx.y == 0) ? W0 : (blockIdx.y == 1) ? W1 : W2;
    unsigned short* T = (blockIdx.y == 0) ? T0 : (blockIdx.y == 1) ? T1 : T2;
    __shared__ float lds[64][65];
    const int tx = blockIdx.x & 3;
    const int ty = blockIdx.x >> 2;
    const int t = threadIdx.x;
    const int r = t >> 6;
    const int c = t & 63;
#pragma unroll
    for (int i = 0; i < 16; ++i) {
        int row = ty * 64 + r + i * 4;
        lds[r + i * 4][c] = W[row * 256 + tx * 64 + c];
    }
    __syncthreads();
#pragma unroll
    for (int i = 0; i < 16; ++i) {
        int orow = tx * 64 + r + i * 4;
        T[orow * 256 + ty * 64 + c] = f2bf(lds[c][r + i * 4]);
    }
}

// ---------------------------------------------------------------------------
// LayerNorm + ReLU, one wave per row of 256
// ---------------------------------------------------------------------------
__global__ __launch_bounds__(256) void ln_relu_kernel(
        const float* __restrict__ x, const float* __restrict__ g,
        const float* __restrict__ b, float* __restrict__ y, int nrows) {
    int row = blockIdx.x * 4 + (threadIdx.x >> 6);
    if (row >= nrows) return;
    int lane = threadIdx.x & 63;
    float4 v = ((const float4*)(x + (size_t)row * D_DIM))[lane];
    float s = v.x + v.y + v.z + v.w;
    float s2 = v.x * v.x + v.y * v.y + v.z * v.z + v.w * v.w;
#pragma unroll
    for (int m = 32; m >= 1; m >>= 1) {
        s += __shfl_xor(s, m, 64);
        s2 += __shfl_xor(s2, m, 64);
    }
    float mean = s * (1.f / D_DIM);
    float var = s2 * (1.f / D_DIM) - mean * mean;
    float rstd = rsqrtf(var + EPS_LN);
    float4 gv = ((const float4*)g)[lane];
    float4 bv = ((const float4*)b)[lane];
    float4 o;
    o.x = fmaxf((v.x - mean) * rstd * gv.x + bv.x, 0.f);
    o.y = fmaxf((v.y - mean) * rstd * gv.y + bv.y, 0.f);
    o.z = fmaxf((v.z - mean) * rstd * gv.z + bv.z, 0.f);
    o.w = fmaxf((v.w - mean) * rstd * gv.w + bv.w, 0.f);
    ((float4*)(y + (size_t)row * D_DIM))[lane] = o;
}

// ---------------------------------------------------------------------------
// bf16-MFMA GEMM via global_load_lds: out[M,256] = A[M,256]@W + bias (+res).
// A fp32 staged raw into LDS (converted bf16 at fragment read); W bf16
// pre-transposed.  128x128 tile, 4 waves, wave 64x64 (4x4 of 16x16x32).
// XOR-swizzled LDS (source-side swizzle since LDS dest is lane-contiguous):
//   A granule(16B) P = G ^ (row&7); B granule P = G ^ ((row>>1)&3).
// Double-buffered, one __syncthreads per K-iter.
// ---------------------------------------------------------------------------
template <int OUT_BF16, int HAS_RES>
__global__ __launch_bounds__(256, 3) void gemm256_kernel(
        const float* __restrict__ A, const unsigned short* __restrict__ Wt,
        const float* __restrict__ bias, const float* __restrict__ res,
        void* __restrict__ out, int M) {
    __shared__ float As[2][128 * 32];          // 16 KB per buf, swizzled
    __shared__ unsigned short Bs[2][128 * 32]; // 8 KB per buf, swizzled
    const int n0 = blockIdx.x * 128;
    const int m0 = blockIdx.y * 128;
    const int t = threadIdx.x;
    const int lane = t & 63;
    const int wave = t >> 6;
    const int q = lane >> 4;
    const int l16 = lane & 15;
    const int wm = (wave & 1) * 64;
    const int wn = (wave >> 1) * 64;

    // A staging: 4 segments/wave, segment = 8 rows x 128B.
    const int rowLA = lane >> 3;                    // 0..7 within segment
    const int GA = (lane & 7) ^ (rowLA & 7);        // logical granule
    // B staging: 2 segments/wave, segment = 16 rows x 64B.
    const int rowLB = lane >> 2;                    // 0..15 within segment
    const int GB = (lane & 3) ^ ((lane >> 3) & 3);  // logical granule

    auto stage = [&](int buf, int kt) {
#pragma unroll
        for (int i = 0; i < 4; ++i) {
            int s = wave * 4 + i;
            int row = m0 + s * 8 + rowLA;
            row = row < M ? row : (M - 1);          // clamp (valid mem, rows unused)
            async_copy16(A + (size_t)row * 256 + kt * 32 + GA * 4,
                         &As[buf][s * 256]);
        }
#pragma unroll
        for (int i = 0; i < 2; ++i) {
            int s = wave * 2 + i;
            int row = n0 + s * 16 + rowLB;
            async_copy16(Wt + (size_t)row * 256 + kt * 32 + GB * 8,
                         &Bs[buf][s * 512]);
        }
    };

    floatx4 acc[4][4] = {};

    stage(0, 0);
    __syncthreads();    // vmcnt(0) drain + barrier: buffer 0 ready

    for (int kt = 0; kt < 8; ++kt) {
        const int cur = kt & 1;
        if (kt < 7) stage(cur ^ 1, kt + 1);   // async, lands by next barrier
        bf16x8 af[4], bfr[4];
#pragma unroll
        for (int mi = 0; mi < 4; ++mi) {
            int r = wm + mi * 16 + l16;
            int P0 = (2 * q) ^ (r & 7);
            float4 f0 = *(const float4*)&As[cur][r * 32 + P0 * 4];
            float4 f1 = *(const float4*)&As[cur][r * 32 + (P0 ^ 1) * 4];
            af[mi] = cvt_frag(f0, f1);
        }
#pragma unroll
        for (int ni = 0; ni < 4; ++ni) {
            int r = wn + ni * 16 + l16;
            int P = q ^ ((r >> 1) & 3);
            bfr[ni] = __builtin_bit_cast(bf16x8,
                *(const ushortx8*)&Bs[cur][r * 32 + P * 8]);
        }
#pragma unroll
        for (int mi = 0; mi < 4; ++mi)
#pragma unroll
            for (int ni = 0; ni < 4; ++ni)
                acc[mi][ni] = __builtin_amdgcn_mfma_f32_16x16x32_bf16(
                    af[mi], bfr[ni], acc[mi][ni], 0, 0, 0);
        __syncthreads();   // reads(cur) done before next iter overwrites cur;
                           // also drains next-tile loads (m97 structure)
    }

    // epilogue: D[row = q*4+r][col = l16] per 16x16 tile
#pragma unroll
    for (int mi = 0; mi < 4; ++mi) {
#pragma unroll
        for (int ni = 0; ni < 4; ++ni) {
            int col = n0 + wn + ni * 16 + l16;
            float bcol = bias[col];
#pragma unroll
            for (int r = 0; r < 4; ++r) {
                int row = m0 + wm + mi * 16 + q * 4 + r;
                if (row < M) {
                    float v = acc[mi][ni][r] + bcol;
                    if (HAS_RES) v += res[(size_t)row * 256 + col];
                    if (OUT_BF16)
                        ((unsigned short*)out)[(size_t)row * 256 + col] = f2bf(v);
                    else
                        ((float*)out)[(size_t)row * 256 + col] = v;
                }
            }
        }
    }
}

// ---------------------------------------------------------------------------
// CSR build: histogram, single-block scan, scatter (stores SOURCE ids)
// ---------------------------------------------------------------------------
__global__ void hist_kernel(const int* __restrict__ tgt, int* __restrict__ counts, int E) {
    int i = blockIdx.x * 256 + threadIdx.x;
    if (i < E) atomicAdd(&counts[tgt[i]], 1);
}

__global__ __launch_bounds__(1024) void scan_kernel(
        const int* __restrict__ counts, int* __restrict__ offs, int n) {
    __shared__ int lds[1024];
    int t = threadIdx.x;
    int CH = (n + 1023) >> 10;
    int beg = t * CH, end = min(beg + CH, n);
    int s = 0;
    for (int i = beg; i < end; ++i) s += counts[i];
    lds[t] = s;
    __syncthreads();
    for (int off = 1; off < 1024; off <<= 1) {
        int v = (t >= off) ? lds[t - off] : 0;
        __syncthreads();
        lds[t] += v;
        __syncthreads();
    }
    int run = lds[t] - s;
    for (int i = beg; i < end; ++i) { offs[i] = run; run += counts[i]; }
    if (t == 1023) offs[n] = lds[1023];
}

__global__ void scatter_kernel(const int* __restrict__ tgt, const int* __restrict__ src,
                               const int* __restrict__ offs, int* __restrict__ cursor,
                               int* __restrict__ slist, int E) {
    int i = blockIdx.x * 256 + threadIdx.x;
    if (i < E) {
        int tg = tgt[i];
        int p = atomicAdd(&cursor[tg], 1);
        slist[offs[tg] + p] = src[i];   // store source node id directly
    }
}

// ---------------------------------------------------------------------------
// Per-target fused: edge softmax + aggregation + gat_bias + residual + LN2 +
// relu.  One wave per target; lane l owns features 4l..4l+3 (head = l>>3);
// per-head dot via shfl_xor {1,2,4}; next edge's row prefetched.
// ---------------------------------------------------------------------------
__global__ __launch_bounds__(256) void aggregate_kernel(
        const unsigned short* __restrict__ xl, const float* __restrict__ xr,
        const float* __restrict__ prev, const int* __restrict__ slist,
        const int* __restrict__ offs, const float* __restrict__ att,
        const float* __restrict__ gbias, const float* __restrict__ g2,
        const float* __restrict__ b2, float* __restrict__ x_skip,
        float* __restrict__ h2, int nsp) {
    int tgt = blockIdx.x * 4 + (threadIdx.x >> 6);
    if (tgt >= nsp) return;
    int lane = threadIdx.x & 63;
    float4 xrv = ((const float4*)(xr + (size_t)tgt * D_DIM))[lane];
    float4 attv = ((const float4*)att)[lane];
    float acc0 = 0.f, acc1 = 0.f, acc2 = 0.f, acc3 = 0.f, den = 0.f;
    int beg = offs[tgt], end = offs[tgt + 1];

    ushortx4 row = {};
    if (beg < end) {
        int src = slist[beg];
        row = ((const ushortx4*)(xl + (size_t)src * D_DIM))[lane];
    }
    for (int i = beg; i < end; ++i) {
        ushortx4 row_n = {};
        if (i + 1 < end) {
            int s1 = slist[i + 1];
            row_n = ((const ushortx4*)(xl + (size_t)s1 * D_DIM))[lane];
        }
        float x0 = bf2f(row[0]), x1 = bf2f(row[1]), x2 = bf2f(row[2]), x3 = bf2f(row[3]);
        float t0 = x0 + xrv.x, t1 = x1 + xrv.y, t2 = x2 + xrv.z, t3 = x3 + xrv.w;
        t0 = t0 > 0.f ? t0 : NEG_SLOPE * t0;
        t1 = t1 > 0.f ? t1 : NEG_SLOPE * t1;
        t2 = t2 > 0.f ? t2 : NEG_SLOPE * t2;
        t3 = t3 > 0.f ? t3 : NEG_SLOPE * t3;
        float p = t0 * attv.x + t1 * attv.y + t2 * attv.z + t3 * attv.w;
        p += __shfl_xor(p, 1, 64);
        p += __shfl_xor(p, 2, 64);
        p += __shfl_xor(p, 4, 64);
        float ex = __expf(p);
        den += ex;
        acc0 += ex * x0; acc1 += ex * x1; acc2 += ex * x2; acc3 += ex * x3;
        row = row_n;
    }
    float rden = 1.f / (den + 1e-16f);
    float4 pv = ((const float4*)(prev + (size_t)tgt * D_DIM))[lane];
    float4 gb = ((const float4*)gbias)[lane];
    float v0 = pv.x + acc0 * rden + gb.x;
    float v1 = pv.y + acc1 * rden + gb.y;
    float v2 = pv.z + acc2 * rden + gb.z;
    float v3 = pv.w + acc3 * rden + gb.w;
    float s = v0 + v1 + v2 + v3;
    float s2 = v0 * v0 + v1 * v1 + v2 * v2 + v3 * v3;
#pragma unroll
    for (int m = 32; m >= 1; m >>= 1) {
        s += __shfl_xor(s, m, 64);
        s2 += __shfl_xor(s2, m, 64);
    }
    float mean = s * (1.f / D_DIM);
    float var = s2 * (1.f / D_DIM) - mean * mean;
    float rstd = rsqrtf(var + EPS_LN);
    float4 g2v = ((const float4*)g2)[lane];
    float4 b2v = ((const float4*)b2)[lane];
    float4 xs; xs.x = v0; xs.y = v1; xs.z = v2; xs.w = v3;
    ((float4*)(x_skip + (size_t)tgt * D_DIM))[lane] = xs;
    float4 h;
    h.x = fmaxf((v0 - mean) * rstd * g2v.x + b2v.x, 0.f);
    h.y = fmaxf((v1 - mean) * rstd * g2v.y + b2v.y, 0.f);
    h.z = fmaxf((v2 - mean) * rstd * g2v.z + b2v.z, 0.f);
    h.w = fmaxf((v3 - mean) * rstd * g2v.w + b2v.w, 0.f);
    ((float4*)(h2 + (size_t)tgt * D_DIM))[lane] = h;
}

// ---------------------------------------------------------------------------
extern "C" void kernel_launch(void* const* d_in, const int* in_sizes, int n_in,
                              void* d_out, int out_size, void* d_ws, size_t ws_size,
                              hipStream_t stream) {
    const float* proj = (const float*)d_in[0];
    const float* prev = (const float*)d_in[1];
    const float* Wl   = (const float*)d_in[2];
    const float* bl   = (const float*)d_in[3];
    const float* Wr   = (const float*)d_in[4];
    const float* br   = (const float*)d_in[5];
    const float* att  = (const float*)d_in[6];
    const float* gbias= (const float*)d_in[7];
    const float* ln1g = (const float*)d_in[8];
    const float* ln1b = (const float*)d_in[9];
    const float* ln2g = (const float*)d_in[10];
    const float* ln2b = (const float*)d_in[11];
    const float* Wm   = (const float*)d_in[12];
    const float* mb   = (const float*)d_in[13];
    const int* esrc   = (const int*)d_in[14];
    const int* etgt   = (const int*)d_in[15];

    const int NP = in_sizes[0] / D_DIM;   // 400000
    const int NS = in_sizes[1] / D_DIM;   // 40000
    const int E  = in_sizes[14];          // 400000

    char* base = (char*)d_ws;
    size_t off = 0;
    auto carve = [&](size_t bytes) {
        char* p = base + off;
        off += (bytes + 255) & ~(size_t)255;
        return p;
    };
    unsigned short* xl    = (unsigned short*)carve((size_t)NP * D_DIM * 2);
    float* x_agg          = (float*)carve((size_t)NS * D_DIM * 4);
    float* xr             = (float*)carve((size_t)NS * D_DIM * 4);
    float* x_skip         = (float*)carve((size_t)NS * D_DIM * 4);
    float* h2             = (float*)carve((size_t)NS * D_DIM * 4);
    unsigned short* Wt_l  = (unsigned short*)carve((size_t)D_DIM * D_DIM * 2);
    unsigned short* Wt_r  = (unsigned short*)carve((size_t)D_DIM * D_DIM * 2);
    unsigned short* Wt_m  = (unsigned short*)carve((size_t)D_DIM * D_DIM * 2);
    int* counts           = (int*)carve((size_t)NS * 4 * 2);
    int* cursor           = counts + NS;
    int* offs             = (int*)carve((size_t)(NS + 1) * 4);
    int* slist            = (int*)carve((size_t)E * 4);

    hipMemsetAsync(counts, 0, (size_t)NS * 4 * 2, stream);

    wtrans_kernel<<<dim3(16, 3), 256, 0, stream>>>(Wl, Wr, Wm, Wt_l, Wt_r, Wt_m);

    ln_relu_kernel<<<(NS + 3) / 4, 256, 0, stream>>>(prev, ln1g, ln1b, x_agg, NS);

    // xr = x_agg @ Wr + br (fp32 out)
    gemm256_kernel<0, 0><<<dim3(2, (NS + 127) / 128), 256, 0, stream>>>(
        x_agg, Wt_r, br, nullptr, (void*)xr, NS);

    // xl = proj @ Wl + bl (bf16 out)
    gemm256_kernel<1, 0><<<dim3(2, (NP + 127) / 128), 256, 0, stream>>>(
        proj, Wt_l, bl, nullptr, (void*)xl, NP);

    // CSR build
    hist_kernel<<<(E + 255) / 256, 256, 0, stream>>>(etgt, counts, E);
    scan_kernel<<<1, 1024, 0, stream>>>(counts, offs, NS);
    scatter_kernel<<<(E + 255) / 256, 256, 0, stream>>>(etgt, esrc, offs, cursor, slist, E);

    // fused edge softmax + aggregation + residual + LN2 + relu
    aggregate_kernel<<<(NS + 3) / 4, 256, 0, stream>>>(
        xl, xr, prev, slist, offs, att, gbias, ln2g, ln2b, x_skip, h2, NS);

    // out = x_skip + h2 @ mlp_W + mlp_b
    gemm256_kernel<0, 1><<<dim3(2, (NS + 127) / 128), 256, 0, stream>>>(
        h2, Wt_m, mb, x_skip, d_out, NS);
}